// Round 1
// 93.589 us; speedup vs baseline: 1.0173x; 1.0173x over previous
//
#include <hip/hip_runtime.h>
#include <math.h>

#define NMAX 3008
#define NCH  47       // ceil(3008/64) chunks
#define CAPC 128      // member compaction capacity
#define NCLS 80
#define TB   512      // threads per block (8 waves)
#define IC   6        // i-chunks for rank (6*512 >= 3000)
#define JC   16       // j-chunks
#define JCH  192
#define RB   (IC*JC)  // 96 rank blocks

// ---- workspace layout (bytes) ----
#define WS_DONE   0                         // u32 done counter
#define WS_FSCORE 16                        // float[NMAX] frozen score by box
#define WS_RANKC  (WS_FSCORE + 4*NMAX)      // u64[NMAX]: gt | eqlt<<16 | eq<<32

// full-wave (64) max via DPP (VALU latency); uniform result in all lanes.
__device__ __forceinline__ float wave_max64(float x) {
    int v;
    v = __float_as_int(x);
    x = fmaxf(x, __int_as_float(__builtin_amdgcn_update_dpp(v, v, 0x111, 0xf, 0xf, false)));
    v = __float_as_int(x);
    x = fmaxf(x, __int_as_float(__builtin_amdgcn_update_dpp(v, v, 0x112, 0xf, 0xf, false)));
    v = __float_as_int(x);
    x = fmaxf(x, __int_as_float(__builtin_amdgcn_update_dpp(v, v, 0x114, 0xf, 0xf, false)));
    v = __float_as_int(x);
    x = fmaxf(x, __int_as_float(__builtin_amdgcn_update_dpp(v, v, 0x118, 0xf, 0xf, false)));
    v = __float_as_int(x);
    x = fmaxf(x, __int_as_float(__builtin_amdgcn_update_dpp(v, v, 0x142, 0xa, 0xf, false)));
    v = __float_as_int(x);
    x = fmaxf(x, __int_as_float(__builtin_amdgcn_update_dpp(v, v, 0x143, 0xc, 0xf, false)));
    return __int_as_float(__builtin_amdgcn_readlane(__float_as_int(x), 63));
}

// ---------------- kernel 1: per-class soft-NMS (8-wave prep, wave-0 select) ----------------
__global__ void __launch_bounds__(TB)
nms_class_kernel(const float* __restrict__ boxes, const float* __restrict__ scores,
                 const int* __restrict__ idxs, char* __restrict__ ws, int n) {
#pragma clang fp contract(off)
    const int c = blockIdx.x;
    const int tid = threadIdx.x, wid = tid >> 6, lane = tid & 63;
    float* fscore = (float*)(ws + WS_FSCORE);
    unsigned long long* RANKC = (unsigned long long*)(ws + WS_RANKC);

    __shared__ unsigned long long maskS[NCH];
    __shared__ float mx0[CAPC], mx1[CAPC], mx2[CAPC], mx3[CAPC], msc[CAPC];
    __shared__ unsigned short mgid[CAPC];
    __shared__ float D[64 * 64];               // 16 KB
    __shared__ unsigned long long ovMS[64];    // per-row overlap-partner mask (d != 1.0f)
    __shared__ float redS[TB / 64];

    // zero shared counters for the next dispatch (stream-ordered)
    for (int i = c * TB + tid; i < NMAX; i += NCLS * TB) RANKC[i] = 0ull;
    if (c == 0 && tid == 0) *(unsigned*)(ws + WS_DONE) = 0u;

    // phase 1: fused idx load + membership ballot + coord max. Wave w owns
    // chunks t with t%8 == w (same assignment reused in the member-load pass).
    float m = -1e30f;
    for (int t = wid; t < NCH; t += 8) {
        int k = t * 64 + lane;
        bool p = false;
        if (k < n) {
            p = (idxs[k] == c);
            float4 bb = ((const float4*)boxes)[k];
            m = fmaxf(m, fmaxf(fmaxf(bb.x, bb.y), fmaxf(bb.z, bb.w)));
        }
        unsigned long long mk = __ballot(p);
        if (lane == 0) maskS[t] = mk;
    }
    m = wave_max64(m);
    if (lane == 0) redS[wid] = m;
    __syncthreads();
    float mm = redS[0];
#pragma unroll
    for (int w = 1; w < TB / 64; w++) mm = fmaxf(mm, redS[w]);   // order-indep max -> exact
    const float maxcp1 = mm + 1.0f;
    const float off = (float)c * maxcp1;

    // phase 2: member loads; all waves walk the uniform prefix, each loads its chunks
    int run = 0;
    for (int t = 0; t < NCH; t++) {
        unsigned long long mk = maskS[t];
        if ((t & 7) == wid) {
            if ((mk >> lane) & 1ull) {
                int pos = run + __popcll(mk & ((1ull << lane) - 1ull));
                if (pos < CAPC) {
                    int k = t * 64 + lane;
                    float4 bb = ((const float4*)boxes)[k];      // L1/L2-warm
                    mx0[pos] = bb.x + off; mx1[pos] = bb.y + off;
                    mx2[pos] = bb.z + off; mx3[pos] = bb.w + off;
                    msc[pos] = scores[k];
                    mgid[pos] = (unsigned short)k;
                }
            }
        }
        run += __popcll(mk);
    }
    const int cnt = run < CAPC ? run : CAPC;
    __syncthreads();

    if (cnt <= 64) {
        // phase 3 (8 waves): decay rows split across waves; exp(-0.0)==1.0f skip.
        // Also ballot the overlap-partner mask per row: bit j set iff d(row,j)!=1.0f.
        // D is bitwise-symmetric (all IoU ops commutative-exact), so ovMS serves as
        // both "who decays me" and "whom I decay".
        const bool v0 = lane < cnt;
        float c0 = 0, c1 = 0, c2 = 0, c3 = 0;
        if (v0) { c0 = mx0[lane]; c1 = mx1[lane]; c2 = mx2[lane]; c3 = mx3[lane]; }
        const float ab = (c2 - c0) * (c3 - c1);
        for (int i = wid; i < cnt; i += 8) {
            float w0 = mx0[i], w1 = mx1[i], w2 = mx2[i], w3 = mx3[i];
            float aw = (w2 - w0) * (w3 - w1);
            float x1 = fmaxf(w0, c0), y1 = fmaxf(w1, c1);
            float x2 = fminf(w2, c2), y2 = fminf(w3, c3);
            float iw = fmaxf(x2 - x1, 0.f), ih = fmaxf(y2 - y1, 0.f);
            float inter = iw * ih;
            float d = 1.0f;
            if (inter != 0.f) {
                float iou = inter / ((aw + ab) - inter);
                float arg = -(iou * iou) / 0.5f;
                d = (float)exp((double)arg);
            }
            D[i * 64 + lane] = d;
            unsigned long long ov = __ballot(d != 1.0f);
            if (lane == 0) ovMS[i] = ov;
        }
        __syncthreads();

        // phase 4 (wave 0): serial selection — validated bit-exact (r2-r9), now with
        // sparse-overlap early-freeze: any remaining candidate with no remaining
        // overlap partner is frozen at its current score (identity multiplies only,
        // bit-exact), shrinking the serial chain from cnt to ~#overlap-involved.
        if (wid == 0) {
            const bool v0b = lane < cnt;
            float sc = v0b ? msc[lane] : -1.f;
            int g = v0b ? mgid[lane] : 0;
            unsigned long long ovm = v0b ? (ovMS[lane] & ~(1ull << lane)) : 0ull;
            float frz = 0.f;
            for (;;) {
                unsigned long long rem = __ballot(sc >= 0.f);
                if (!rem) break;
                if (sc >= 0.f && (ovm & rem) == 0ull) { frz = sc; sc = -1.f; }  // isolated: freeze now
                rem = __ballot(sc >= 0.f);
                if (!rem) break;
                float M = wave_max64(sc);
                int wm = __ffsll(__ballot(sc == M)) - 1;
                float d = D[wm * 64 + lane];
                if (lane == wm) { frz = M; sc = -1.f; }
                else if (sc >= 0.f) sc = sc * d;
            }
            if (v0b) fscore[g] = frz;
        }
    } else if (wid == 0) {
        // fallback (cnt > 64): validated 2-slot in-loop path
        float sc0 = -1.f, sc1 = -1.f;
        float a0 = 0, a1 = 0, a2 = 0, a3 = 0, b0 = 0, b1 = 0, b2 = 0, b3 = 0;
        int g0 = 0, g1 = 0;
        if (lane < cnt) {
            sc0 = msc[lane];
            a0 = mx0[lane]; a1 = mx1[lane]; a2 = mx2[lane]; a3 = mx3[lane];
            g0 = mgid[lane];
        }
        if (64 + lane < cnt) {
            sc1 = msc[64 + lane];
            b0 = mx0[64 + lane]; b1 = mx1[64 + lane]; b2 = mx2[64 + lane]; b3 = mx3[64 + lane];
            g1 = mgid[64 + lane];
        }
        for (int s = 0; s < cnt; s++) {
            float M = fmaxf(sc0, sc1);
            for (int o = 32; o >= 1; o >>= 1) M = fmaxf(M, __shfl_xor(M, o, 64));
            unsigned long long balA = __ballot(sc0 == M);
            int wm;
            if (balA) wm = __ffsll(balA) - 1;
            else      wm = 64 + __ffsll(__ballot(sc1 == M)) - 1;
            float w0 = mx0[wm], w1 = mx1[wm], w2 = mx2[wm], w3 = mx3[wm];
            if (wm == lane)           { fscore[g0] = M; sc0 = -1.f; }
            else if (wm == 64 + lane) { fscore[g1] = M; sc1 = -1.f; }
            float area_w = (w2 - w0) * (w3 - w1);
            if (sc0 >= 0.f) {
                float x1 = fmaxf(w0, a0), y1 = fmaxf(w1, a1);
                float x2 = fminf(w2, a2), y2 = fminf(w3, a3);
                float iw = fmaxf(x2 - x1, 0.f), ih = fmaxf(y2 - y1, 0.f);
                float inter = iw * ih;
                float area_b = (a2 - a0) * (a3 - a1);
                float iou = inter / ((area_w + area_b) - inter);
                float arg = -(iou * iou) / 0.5f;
                sc0 = sc0 * (float)exp((double)arg);
            }
            if (sc1 >= 0.f) {
                float x1 = fmaxf(w0, b0), y1 = fmaxf(w1, b1);
                float x2 = fminf(w2, b2), y2 = fminf(w3, b3);
                float iw = fmaxf(x2 - x1, 0.f), ih = fmaxf(y2 - y1, 0.f);
                float inter = iw * ih;
                float area_b = (b2 - b0) * (b3 - b1);
                float iou = inter / ((area_w + area_b) - inter);
                float arg = -(iou * iou) / 0.5f;
                sc1 = sc1 * (float)exp((double)arg);
            }
        }
    }
}

// ---------------- kernel 2: fused rank + finalize (last-block pattern) ----------------
__global__ void __launch_bounds__(TB)
rank_finalize_kernel(char* __restrict__ ws, float* __restrict__ out, int n) {
    const int tid = threadIdx.x;
    float* fscore = (float*)(ws + WS_FSCORE);
    unsigned long long* RANKC = (unsigned long long*)(ws + WS_RANKC);
    unsigned* done = (unsigned*)(ws + WS_DONE);

    __shared__ float sv[JCH];

    // ---- rank phase: block = (i-chunk bx, j-chunk by) ----
    const int bx = blockIdx.x % IC;
    const int by = blockIdx.x / IC;
    const int chunk = (n + JC - 1) / JC;
    const int j0 = by * chunk;
    const int jn = min(n - j0, chunk);
    for (int j = tid; j < jn; j += TB) sv[j] = fscore[j0 + j];
    __syncthreads();

    int i = bx * TB + tid;
    if (i < n) {
        float s = fscore[i];
        int gt = 0, eq = 0, eqlt = 0;
        for (int jj = 0; jj < jn; jj++) {
            float x = sv[jj];
            gt   += (x > s) ? 1 : 0;
            eq   += (x == s) ? 1 : 0;
            eqlt += (x == s && (j0 + jj) < i) ? 1 : 0;
        }
        unsigned long long packed = (unsigned long long)(unsigned)gt
                                  | ((unsigned long long)(unsigned)eqlt << 16)
                                  | ((unsigned long long)(unsigned)eq << 32);
        atomicAdd(&RANKC[i], packed);
    }
    __syncthreads();
    __threadfence();

    __shared__ int lastS;
    if (tid == 0) lastS = (atomicAdd(done, 1u) == RB - 1);
    __syncthreads();
    if (!lastS) return;
    __threadfence();   // acquire side: all rank-block atomics visible before gather

    // ---- finalize phase (last-done block only) ----
    __shared__ unsigned short ordL[NMAX];
    __shared__ float          svL[NMAX];
    __shared__ unsigned short slotL[NMAX];
    __shared__ unsigned short batL[NMAX];
    __shared__ unsigned char  tieL[NMAX];
    __shared__ int rstopS;
    if (tid == 0) rstopS = 0;
    __syncthreads();

    for (int b = tid; b < n; b += TB) {
        // device-coherent read (agent-scope atomic load: no RMW round-trip)
        unsigned long long p = __hip_atomic_load(&RANKC[b], __ATOMIC_RELAXED,
                                                 __HIP_MEMORY_SCOPE_AGENT);
        unsigned gt   = (unsigned)(p & 0xffffu);
        unsigned eqlt = (unsigned)((p >> 16) & 0xffffu);
        unsigned eq   = (unsigned)((p >> 32) & 0xffffu);
        int r = (int)(gt + eqlt);
        ordL[r] = (unsigned short)b;
        svL[r] = fscore[b];
        slotL[b] = (unsigned short)b;
        batL[b]  = (unsigned short)b;
        // unsafe group: a member's id < group START (gt); members with id >= gt
        // provably still sit at slot == id when the group is emitted.
        if (eq >= 2 && (unsigned)b < gt) atomicMax(&rstopS, (int)(gt + eq));
    }
    __syncthreads();

    for (int r = tid; r < n; r += TB)
        tieL[r] = (r + 1 < n) && (svL[r] == svL[r + 1]);
    __syncthreads();

    if (rstopS > 0 && tid == 0) {
        const int rstop = rstopS;
        int r = 0;
        while (r < rstop) {
            if (!tieL[r]) {
                int w = ordL[r];
                int j = slotL[w];
                int d = batL[r];
                batL[j] = (unsigned short)d;
                slotL[d] = (unsigned short)j;
                r++;
            } else {
                int g = 1;
                while (tieL[r + g - 1]) g++;
                for (int t = 0; t < g; t++) {
                    int bi = r + t;
                    int bs = slotL[ordL[bi]];
                    for (int q = r + t + 1; q < r + g; q++) {
                        int s2 = slotL[ordL[q]];
                        if (s2 < bs) { bs = s2; bi = q; }
                    }
                    unsigned short w = ordL[bi];
                    ordL[bi] = ordL[r + t];
                    ordL[r + t] = w;
                    int d = batL[r + t];
                    batL[bs] = (unsigned short)d;
                    slotL[d] = (unsigned short)bs;
                }
                r += g;
            }
        }
    }
    __syncthreads();

    for (int r = tid; r < n; r += TB) {
        float s = svL[r];
        out[r] = s;
        out[n + r] = (float)ordL[r];
        out[2 * n + r] = (s > 0.05f) ? 1.f : 0.f;
    }
}

extern "C" void kernel_launch(void* const* d_in, const int* in_sizes, int n_in,
                              void* d_out, int out_size, void* d_ws, size_t ws_size,
                              hipStream_t stream) {
    const float* boxes  = (const float*)d_in[0];  // [N,4] f32
    const float* scores = (const float*)d_in[1];  // [N]   f32
    const int*   idxs   = (const int*)d_in[2];    // [N]   i32
    float* out = (float*)d_out;                   // scores | order | keep (f32)
    char* ws = (char*)d_ws;
    const int n = in_sizes[1];

    nms_class_kernel<<<NCLS, TB, 0, stream>>>(boxes, scores, idxs, ws, n);
    rank_finalize_kernel<<<RB, TB, 0, stream>>>(ws, out, n);
}

// Round 2
// 90.081 us; speedup vs baseline: 1.0569x; 1.0389x over previous
//
#include <hip/hip_runtime.h>
#include <math.h>

#define NMAX 3008
#define NCH  47       // ceil(3008/64) chunks
#define CAPC 128      // member compaction capacity
#define NCLS 80
#define TB   512      // threads per block (8 waves)
#define IC   6        // i-chunks for rank (6*512 >= 3000)
#define JC   16       // j-chunks
#define JCH  192
#define RB   (IC*JC)  // 96 rank blocks

// ---- workspace layout (bytes) ----
#define WS_DONE   0                         // u32 done counter
#define WS_FSCORE 16                        // float[NMAX] frozen score by box
#define WS_RANKC  (WS_FSCORE + 4*NMAX)      // u64[NMAX]: gt | eqlt<<16 | eq<<32

// full-wave (64) max via DPP (VALU latency); uniform result in all lanes.
__device__ __forceinline__ float wave_max64(float x) {
    int v;
    v = __float_as_int(x);
    x = fmaxf(x, __int_as_float(__builtin_amdgcn_update_dpp(v, v, 0x111, 0xf, 0xf, false)));
    v = __float_as_int(x);
    x = fmaxf(x, __int_as_float(__builtin_amdgcn_update_dpp(v, v, 0x112, 0xf, 0xf, false)));
    v = __float_as_int(x);
    x = fmaxf(x, __int_as_float(__builtin_amdgcn_update_dpp(v, v, 0x114, 0xf, 0xf, false)));
    v = __float_as_int(x);
    x = fmaxf(x, __int_as_float(__builtin_amdgcn_update_dpp(v, v, 0x118, 0xf, 0xf, false)));
    v = __float_as_int(x);
    x = fmaxf(x, __int_as_float(__builtin_amdgcn_update_dpp(v, v, 0x142, 0xa, 0xf, false)));
    v = __float_as_int(x);
    x = fmaxf(x, __int_as_float(__builtin_amdgcn_update_dpp(v, v, 0x143, 0xc, 0xf, false)));
    return __int_as_float(__builtin_amdgcn_readlane(__float_as_int(x), 63));
}

// ---------------- kernel 1: per-class soft-NMS (8-wave prep, component-parallel select) ----------------
__global__ void __launch_bounds__(TB)
nms_class_kernel(const float* __restrict__ boxes, const float* __restrict__ scores,
                 const int* __restrict__ idxs, char* __restrict__ ws, int n) {
#pragma clang fp contract(off)
    const int c = blockIdx.x;
    const int tid = threadIdx.x, wid = tid >> 6, lane = tid & 63;
    float* fscore = (float*)(ws + WS_FSCORE);
    unsigned long long* RANKC = (unsigned long long*)(ws + WS_RANKC);

    __shared__ unsigned long long maskS[NCH];
    __shared__ float mx0[CAPC], mx1[CAPC], mx2[CAPC], mx3[CAPC], msc[CAPC];
    __shared__ unsigned short mgid[CAPC];
    __shared__ float D[64 * 64];               // 16 KB
    __shared__ unsigned long long ovMS[64];    // per-row overlap-partner mask (d != 1.0f)
    __shared__ int labS[64];                   // component labels (min lane in component)
    __shared__ float redS[TB / 64];

    // zero shared counters for the next dispatch (stream-ordered)
    for (int i = c * TB + tid; i < NMAX; i += NCLS * TB) RANKC[i] = 0ull;
    if (c == 0 && tid == 0) *(unsigned*)(ws + WS_DONE) = 0u;

    // phase 1: fused idx load + membership ballot + coord max. Wave w owns
    // chunks t with t%8 == w (same assignment reused in the member-load pass).
    float m = -1e30f;
    for (int t = wid; t < NCH; t += 8) {
        int k = t * 64 + lane;
        bool p = false;
        if (k < n) {
            p = (idxs[k] == c);
            float4 bb = ((const float4*)boxes)[k];
            m = fmaxf(m, fmaxf(fmaxf(bb.x, bb.y), fmaxf(bb.z, bb.w)));
        }
        unsigned long long mk = __ballot(p);
        if (lane == 0) maskS[t] = mk;
    }
    m = wave_max64(m);
    if (lane == 0) redS[wid] = m;
    __syncthreads();
    float mm = redS[0];
#pragma unroll
    for (int w = 1; w < TB / 64; w++) mm = fmaxf(mm, redS[w]);   // order-indep max -> exact
    const float maxcp1 = mm + 1.0f;
    const float off = (float)c * maxcp1;

    // phase 2 (parallel): chunk-popcount prefix scan, then each wave loads its
    // chunks directly at known base offsets (replaces the 47-step serial walk).
    int cS = (lane < NCH) ? __popcll(maskS[lane]) : 0;
    int inc = cS;
#pragma unroll
    for (int o = 1; o < 64; o <<= 1) {
        int y = __shfl_up(inc, o, 64);
        if (lane >= o) inc += y;
    }
    const int baseEx = inc - cS;                    // exclusive prefix (chunk = lane)
    const int total = __shfl(inc, NCH - 1, 64);     // total member count
    for (int t = wid; t < NCH; t += 8) {
        unsigned long long mk = maskS[t];
        int bt = __shfl(baseEx, t, 64);
        if ((mk >> lane) & 1ull) {
            int pos = bt + __popcll(mk & ((1ull << lane) - 1ull));
            if (pos < CAPC) {
                int k = t * 64 + lane;
                float4 bb = ((const float4*)boxes)[k];      // L1-warm from phase 1
                mx0[pos] = bb.x + off; mx1[pos] = bb.y + off;
                mx2[pos] = bb.z + off; mx3[pos] = bb.w + off;
                msc[pos] = scores[k];
                mgid[pos] = (unsigned short)k;
            }
        }
    }
    const int cnt = total < CAPC ? total : CAPC;
    __syncthreads();

    if (cnt <= 64) {
        // phase 3 (8 waves): decay rows split across waves; exp(-0.0)==1.0f skip.
        // Also ballot the overlap-partner mask per row: bit j set iff d(row,j)!=1.0f.
        // D is bitwise-symmetric (all IoU ops commutative-exact), so ovMS serves as
        // both "who decays me" and "whom I decay".
        const bool v0 = lane < cnt;
        float c0 = 0, c1 = 0, c2 = 0, c3 = 0;
        if (v0) { c0 = mx0[lane]; c1 = mx1[lane]; c2 = mx2[lane]; c3 = mx3[lane]; }
        const float ab = (c2 - c0) * (c3 - c1);
        for (int i = wid; i < cnt; i += 8) {
            float w0 = mx0[i], w1 = mx1[i], w2 = mx2[i], w3 = mx3[i];
            float aw = (w2 - w0) * (w3 - w1);
            float x1 = fmaxf(w0, c0), y1 = fmaxf(w1, c1);
            float x2 = fminf(w2, c2), y2 = fminf(w3, c3);
            float iw = fmaxf(x2 - x1, 0.f), ih = fmaxf(y2 - y1, 0.f);
            float inter = iw * ih;
            float d = 1.0f;
            if (inter != 0.f) {
                float iou = inter / ((aw + ab) - inter);
                float arg = -(iou * iou) / 0.5f;
                d = (float)exp((double)arg);
            }
            D[i * 64 + lane] = d;
            unsigned long long ov = __ballot(d != 1.0f);
            if (lane == 0) ovMS[i] = ov;
        }
        __syncthreads();

        // phase 4a (wave 0): connected-component labels of the overlap graph via
        // min-label propagation + pointer jumping. Labels converge to the min lane
        // index of each component; guaranteed <= diameter iterations (monotone).
        if (wid == 0) {
            const bool v0b = lane < cnt;
            unsigned long long ovm = v0b ? (ovMS[lane] & ~(1ull << lane)) : 0ull;
            int lab = lane;
            if (ovm != 0ull) {
                for (;;) {
                    labS[lane] = lab;
                    __asm__ volatile("s_waitcnt lgkmcnt(0)" ::: "memory");
                    int mnew = lab;
                    unsigned long long msk = ovm;
                    while (msk) {
                        int j = __ffsll(msk) - 1;
                        msk &= msk - 1;
                        int lj = labS[j];
                        mnew = lj < mnew ? lj : mnew;
                    }
                    int lj2 = labS[mnew];                 // pointer jump (old table, safe)
                    mnew = lj2 < mnew ? lj2 : mnew;
                    unsigned long long ch = __ballot(mnew != lab);
                    lab = mnew;
                    if (!ch) break;
                }
            }
            labS[lane] = lab;   // publish final (singletons: own lane)
        }
        __syncthreads();

        // phase 4b (ALL 8 waves): component-parallel selection. Wave (label&7) owns
        // each component; components are closed under the overlap relation, and
        // cross-component decay is multiplication by exactly 1.0f (identity), so
        // per-component frozen scores are bit-identical to the global sequence.
        // Loop body is the r1-validated selection with sparse-overlap early-freeze.
        {
            const bool mine = (lane < cnt) && ((labS[lane] & 7) == wid);
            float sc = mine ? msc[lane] : -1.f;
            int g = mine ? mgid[lane] : 0;
            unsigned long long ovm = mine ? (ovMS[lane] & ~(1ull << lane)) : 0ull;
            float frz = 0.f;
            for (;;) {
                unsigned long long rem = __ballot(sc >= 0.f);
                if (!rem) break;
                if (sc >= 0.f && (ovm & rem) == 0ull) { frz = sc; sc = -1.f; }  // isolated: freeze
                rem = __ballot(sc >= 0.f);
                if (!rem) break;
                float M = wave_max64(sc);
                int wm = __ffsll(__ballot(sc == M)) - 1;
                float d = D[wm * 64 + lane];
                if (lane == wm) { frz = M; sc = -1.f; }
                else if (sc >= 0.f) sc = sc * d;
            }
            if (mine) fscore[g] = frz;
        }
    } else if (wid == 0) {
        // fallback (cnt > 64): validated 2-slot in-loop path
        float sc0 = -1.f, sc1 = -1.f;
        float a0 = 0, a1 = 0, a2 = 0, a3 = 0, b0 = 0, b1 = 0, b2 = 0, b3 = 0;
        int g0 = 0, g1 = 0;
        if (lane < cnt) {
            sc0 = msc[lane];
            a0 = mx0[lane]; a1 = mx1[lane]; a2 = mx2[lane]; a3 = mx3[lane];
            g0 = mgid[lane];
        }
        if (64 + lane < cnt) {
            sc1 = msc[64 + lane];
            b0 = mx0[64 + lane]; b1 = mx1[64 + lane]; b2 = mx2[64 + lane]; b3 = mx3[64 + lane];
            g1 = mgid[64 + lane];
        }
        for (int s = 0; s < cnt; s++) {
            float M = fmaxf(sc0, sc1);
            for (int o = 32; o >= 1; o >>= 1) M = fmaxf(M, __shfl_xor(M, o, 64));
            unsigned long long balA = __ballot(sc0 == M);
            int wm;
            if (balA) wm = __ffsll(balA) - 1;
            else      wm = 64 + __ffsll(__ballot(sc1 == M)) - 1;
            float w0 = mx0[wm], w1 = mx1[wm], w2 = mx2[wm], w3 = mx3[wm];
            if (wm == lane)           { fscore[g0] = M; sc0 = -1.f; }
            else if (wm == 64 + lane) { fscore[g1] = M; sc1 = -1.f; }
            float area_w = (w2 - w0) * (w3 - w1);
            if (sc0 >= 0.f) {
                float x1 = fmaxf(w0, a0), y1 = fmaxf(w1, a1);
                float x2 = fminf(w2, a2), y2 = fminf(w3, a3);
                float iw = fmaxf(x2 - x1, 0.f), ih = fmaxf(y2 - y1, 0.f);
                float inter = iw * ih;
                float area_b = (a2 - a0) * (a3 - a1);
                float iou = inter / ((area_w + area_b) - inter);
                float arg = -(iou * iou) / 0.5f;
                sc0 = sc0 * (float)exp((double)arg);
            }
            if (sc1 >= 0.f) {
                float x1 = fmaxf(w0, b0), y1 = fmaxf(w1, b1);
                float x2 = fminf(w2, b2), y2 = fminf(w3, b3);
                float iw = fmaxf(x2 - x1, 0.f), ih = fmaxf(y2 - y1, 0.f);
                float inter = iw * ih;
                float area_b = (b2 - b0) * (b3 - b1);
                float iou = inter / ((area_w + area_b) - inter);
                float arg = -(iou * iou) / 0.5f;
                sc1 = sc1 * (float)exp((double)arg);
            }
        }
    }
}

// ---------------- kernel 2: fused rank + finalize (last-block pattern) ----------------
__global__ void __launch_bounds__(TB)
rank_finalize_kernel(char* __restrict__ ws, float* __restrict__ out, int n) {
    const int tid = threadIdx.x;
    float* fscore = (float*)(ws + WS_FSCORE);
    unsigned long long* RANKC = (unsigned long long*)(ws + WS_RANKC);
    unsigned* done = (unsigned*)(ws + WS_DONE);

    __shared__ float sv[JCH];

    // ---- rank phase: block = (i-chunk bx, j-chunk by) ----
    const int bx = blockIdx.x % IC;
    const int by = blockIdx.x / IC;
    const int chunk = (n + JC - 1) / JC;
    const int j0 = by * chunk;
    const int jn = min(n - j0, chunk);
    for (int j = tid; j < jn; j += TB) sv[j] = fscore[j0 + j];
    __syncthreads();

    int i = bx * TB + tid;
    if (i < n) {
        float s = fscore[i];
        int gt = 0, eq = 0, eqlt = 0;
        for (int jj = 0; jj < jn; jj++) {
            float x = sv[jj];
            gt   += (x > s) ? 1 : 0;
            eq   += (x == s) ? 1 : 0;
            eqlt += (x == s && (j0 + jj) < i) ? 1 : 0;
        }
        unsigned long long packed = (unsigned long long)(unsigned)gt
                                  | ((unsigned long long)(unsigned)eqlt << 16)
                                  | ((unsigned long long)(unsigned)eq << 32);
        atomicAdd(&RANKC[i], packed);
    }
    __syncthreads();
    __threadfence();

    __shared__ int lastS;
    if (tid == 0) lastS = (atomicAdd(done, 1u) == RB - 1);
    __syncthreads();
    if (!lastS) return;
    __threadfence();   // acquire side: all rank-block atomics visible before gather

    // ---- finalize phase (last-done block only) ----
    __shared__ unsigned short ordL[NMAX];
    __shared__ float          svL[NMAX];
    __shared__ unsigned short slotL[NMAX];
    __shared__ unsigned short batL[NMAX];
    __shared__ unsigned char  tieL[NMAX];
    __shared__ int rstopS;
    if (tid == 0) rstopS = 0;
    __syncthreads();

    for (int b = tid; b < n; b += TB) {
        // device-coherent read (agent-scope atomic load: no RMW round-trip)
        unsigned long long p = __hip_atomic_load(&RANKC[b], __ATOMIC_RELAXED,
                                                 __HIP_MEMORY_SCOPE_AGENT);
        unsigned gt   = (unsigned)(p & 0xffffu);
        unsigned eqlt = (unsigned)((p >> 16) & 0xffffu);
        unsigned eq   = (unsigned)((p >> 32) & 0xffffu);
        int r = (int)(gt + eqlt);
        ordL[r] = (unsigned short)b;
        svL[r] = fscore[b];
        slotL[b] = (unsigned short)b;
        batL[b]  = (unsigned short)b;
        // unsafe group: a member's id < group START (gt); members with id >= gt
        // provably still sit at slot == id when the group is emitted.
        if (eq >= 2 && (unsigned)b < gt) atomicMax(&rstopS, (int)(gt + eq));
    }
    __syncthreads();

    for (int r = tid; r < n; r += TB)
        tieL[r] = (r + 1 < n) && (svL[r] == svL[r + 1]);
    __syncthreads();

    if (rstopS > 0 && tid == 0) {
        const int rstop = rstopS;
        int r = 0;
        while (r < rstop) {
            if (!tieL[r]) {
                int w = ordL[r];
                int j = slotL[w];
                int d = batL[r];
                batL[j] = (unsigned short)d;
                slotL[d] = (unsigned short)j;
                r++;
            } else {
                int g = 1;
                while (tieL[r + g - 1]) g++;
                for (int t = 0; t < g; t++) {
                    int bi = r + t;
                    int bs = slotL[ordL[bi]];
                    for (int q = r + t + 1; q < r + g; q++) {
                        int s2 = slotL[ordL[q]];
                        if (s2 < bs) { bs = s2; bi = q; }
                    }
                    unsigned short w = ordL[bi];
                    ordL[bi] = ordL[r + t];
                    ordL[r + t] = w;
                    int d = batL[r + t];
                    batL[bs] = (unsigned short)d;
                    slotL[d] = (unsigned short)bs;
                }
                r += g;
            }
        }
    }
    __syncthreads();

    for (int r = tid; r < n; r += TB) {
        float s = svL[r];
        out[r] = s;
        out[n + r] = (float)ordL[r];
        out[2 * n + r] = (s > 0.05f) ? 1.f : 0.f;
    }
}

extern "C" void kernel_launch(void* const* d_in, const int* in_sizes, int n_in,
                              void* d_out, int out_size, void* d_ws, size_t ws_size,
                              hipStream_t stream) {
    const float* boxes  = (const float*)d_in[0];  // [N,4] f32
    const float* scores = (const float*)d_in[1];  // [N]   f32
    const int*   idxs   = (const int*)d_in[2];    // [N]   i32
    float* out = (float*)d_out;                   // scores | order | keep (f32)
    char* ws = (char*)d_ws;
    const int n = in_sizes[1];

    nms_class_kernel<<<NCLS, TB, 0, stream>>>(boxes, scores, idxs, ws, n);
    rank_finalize_kernel<<<RB, TB, 0, stream>>>(ws, out, n);
}